// Round 6
// baseline (44.714 us; speedup 1.0000x reference)
//
#include <hip/hip_runtime.h>
#include <math.h>

#define SEQ_LEN 4096
#define KSZ 128
#define OUT_LEN 3969
#define BATCH 8192
#define NB 1024          // main grid blocks
#define TAIL_NB 16       // tail kernel blocks

// ---- DPP wave-64 sum, result broadcast wave-uniform via readlane 63 ----
// Canonical GCN sequence: row_shr 1/2/4/8 (intra-16 inclusive tails),
// row_bcast15 (lane15->16..31, lane47->48..63), row_bcast31 (lane31->32..63),
// then lane 63 holds the full sum. Invalid-lane reads contribute 0 (bc=1).
template <int CTRL>
__device__ __forceinline__ float dpp_add(float x) {
    const int m = __builtin_amdgcn_update_dpp(0, __float_as_int(x), CTRL, 0xf, 0xf, true);
    return x + __int_as_float(m);
}
__device__ __forceinline__ float wave_sum_uniform(float x) {
    x = dpp_add<0x111>(x);   // row_shr:1
    x = dpp_add<0x112>(x);   // row_shr:2
    x = dpp_add<0x114>(x);   // row_shr:4
    x = dpp_add<0x118>(x);   // row_shr:8
    x = dpp_add<0x142>(x);   // row_bcast:15
    x = dpp_add<0x143>(x);   // row_bcast:31
    return __int_as_float(__builtin_amdgcn_readlane(__float_as_int(x), 63));
}

// Main pass: one wave = one row, 2 rows/wave, no barriers in the row loop.
// 16 float4 loads in flight, DPP reduce (VALU, ~10x lower latency than
// ds_swizzle butterfly) shrinks the per-row no-memory-issue bubble.
__global__ __launch_bounds__(256, 4) void conv1d_train_main(
    const float* __restrict__ x, const float* __restrict__ y,
    const float* __restrict__ kern, const float* __restrict__ bias,
    float* __restrict__ partial)
{
    __shared__ float P[KSZ];      // inclusive prefix sums of kernel
    __shared__ float sl[4][256];  // per-wave partials for block combine

    const int tid  = threadIdx.x;
    const int wave = tid >> 6;
    const int lane = tid & 63;

    if (tid < KSZ) P[tid] = kern[tid];
    __syncthreads();
#pragma unroll
    for (int off = 1; off < KSZ; off <<= 1) {   // Hillis-Steele scan
        float v = 0.f;
        if (tid < KSZ) {
            v = P[tid];
            if (tid >= off) v += P[tid - off];
        }
        __syncthreads();
        if (tid < KSZ) P[tid] = v;
        __syncthreads();
    }
    const float ksum = P[KSZ - 1];
    const float bs   = bias[0];

    // Per-lane edge-correction weights.
    // head lane l<32: elems j=4l..4l+3, weight P[j]-ksum  (j=127 -> 0)
    // tail lane l>=32: elem 3968+4(l-32)+q, m=elem-3969, weight -P[m]; m=-1 -> 0
    float w0, w1, w2, w3;
    if (lane < 32) {
        const int j = 4 * lane;
        w0 = P[j] - ksum; w1 = P[j + 1] - ksum;
        w2 = P[j + 2] - ksum; w3 = P[j + 3] - ksum;
    } else {
        const int m = 4 * (lane - 32) - 1;
        w0 = (m >= 0) ? -P[m] : 0.f;
        w1 = -P[m + 1]; w2 = -P[m + 2]; w3 = -P[m + 3];
    }

    float g0 = 0.f, g1 = 0.f, g2 = 0.f, g3 = 0.f;  // dconv-weighted edge accum
    float C0 = 0.f, db = 0.f;

    const int wg = blockIdx.x * 4 + wave;

    for (int b = wg; b < BATCH; b += NB * 4) {
        const float4* xr = reinterpret_cast<const float4*>(x + (size_t)b * SEQ_LEN);
        float4 r[16];
#pragma unroll
        for (int i = 0; i < 16; ++i) r[i] = xr[i * 64 + lane];
        const float yv = y[b];                       // broadcast load

        float tot = 0.f;
#pragma unroll
        for (int i = 0; i < 16; ++i) tot += (r[i].x + r[i].y) + (r[i].z + r[i].w);

        const float4 e = (lane < 32) ? r[0] : r[15];
        const float corr = ((w0 * e.x + w1 * e.y) + (w2 * e.z + w3 * e.w));

        const float t = wave_sum_uniform(tot);       // wave-uniform scalars
        const float c = wave_sum_uniform(corr);

        const float logits = (ksum * t + c) * (1.f / (float)OUT_LEN) + bs;
        const float sig    = 1.f / (1.f + expf(-logits));
        const float dconv  = (sig - yv) * (1.f / (float)OUT_LEN);

        g0 += dconv * e.x; g1 += dconv * e.y;
        g2 += dconv * e.z; g3 += dconv * e.w;
        C0 += dconv * t;   db += dconv;
    }

    // Per-wave writeout to LDS: [0..126]=G, [127]=C0, [128..254]=H, [255]=db
    if (lane < 32) {
        const int j = 4 * lane;
        sl[wave][j]     = g0;
        sl[wave][j + 1] = g1;
        sl[wave][j + 2] = g2;
        if (j + 3 < 127) sl[wave][j + 3] = g3;   // skip unused G[127]
    } else {
        const int s0 = 4 * lane - 1;             // slot = 128 + m
        if (lane > 32) sl[wave][s0] = g0;        // lane 32 q=0 -> m=-1, skip
        sl[wave][s0 + 1] = g1;
        sl[wave][s0 + 2] = g2;
        sl[wave][s0 + 3] = g3;                   // lane 63 -> slot 254
    }
    if (lane == 0) {
        // C0/db were accumulated from wave-uniform values: lane 0's copy is
        // the wave's value (all lanes identical).
        sl[wave][127] = C0; sl[wave][255] = db;
    }
    __syncthreads();
    if (tid < 256) {
        const float s = (sl[0][tid] + sl[1][tid]) + (sl[2][tid] + sl[3][tid]);
        partial[(size_t)blockIdx.x * 256 + tid] = s;   // coalesced 1KB/block
    }
}

// Tail: 16 blocks x 1024 threads stream the 1024x256 partial matrix fully
// coalesced -> partial2[16][256]; last-arriving block (atomic counter, no
// reset needed: +16 per launch, exactly one old==15 mod 16) sums the 16 rows,
// does the one-time 127-step prefix/suffix scan, writes the 129 outputs.
__global__ __launch_bounds__(1024) void conv1d_train_tail(
    const float* __restrict__ partial, float* __restrict__ partial2,
    unsigned* __restrict__ counter,
    const float* __restrict__ kern, const float* __restrict__ bias,
    float* __restrict__ out)
{
    __shared__ float sl[4][256];
    __shared__ float colsum[256];
    __shared__ unsigned lastFlag;

    const int tid  = threadIdx.x;
    const int col  = tid & 255;
    const int rsub = tid >> 8;                  // 0..3
    const int base = blockIdx.x * 64;

    float a = 0.f;
#pragma unroll
    for (int j = 0; j < 16; ++j)
        a += partial[(size_t)(base + j * 4 + rsub) * 256 + col];  // coalesced

    sl[rsub][col] = a;
    __syncthreads();
    if (tid < 256)
        partial2[(size_t)blockIdx.x * 256 + tid] =
            (sl[0][tid] + sl[1][tid]) + (sl[2][tid] + sl[3][tid]);

    __threadfence();            // release partial2 (every thread fences own writes)
    __syncthreads();
    if (tid == 0) {
        const unsigned old = atomicAdd(counter, 1u);
        lastFlag = ((old & 15u) == 15u) ? 1u : 0u;
    }
    __syncthreads();
    if (!lastFlag) return;

    __threadfence();            // acquire
    if (tid < 256) {
        float s = 0.f;
#pragma unroll
        for (int g = 0; g < TAIL_NB; ++g) s += partial2[(size_t)g * 256 + tid];
        colsum[tid] = s;
    }
    __syncthreads();

    if (tid < 128) {
        const float C0 = colsum[127];
        float pre = 0.f, suf = 0.f;
        for (int j = 0; j < 127; ++j) {
            const float g = colsum[j];           // broadcast
            const float h = colsum[128 + j];
            if (j < tid)  pre += g;
            if (j >= tid) suf += h;
        }
        const float dk = (C0 - pre - suf) * (1.f / (float)BATCH);
        out[tid] = kern[tid] - dk;
    }
    if (tid == 0) {
        const float dbo = colsum[255] * ((float)OUT_LEN / (float)BATCH);
        out[128] = bias[0] - dbo;
    }
}

extern "C" void kernel_launch(void* const* d_in, const int* in_sizes, int n_in,
                              void* d_out, int out_size, void* d_ws, size_t ws_size,
                              hipStream_t stream) {
    (void)in_sizes; (void)n_in; (void)out_size; (void)ws_size;
    const float* x    = (const float*)d_in[0];
    const float* y    = (const float*)d_in[1];
    const float* kern = (const float*)d_in[2];
    const float* bias = (const float*)d_in[3];
    float* out = (float*)d_out;

    // ws layout: partial[NB*256], partial2[TAIL_NB*256], counter.
    float*    partial  = (float*)d_ws;
    float*    partial2 = partial + (size_t)NB * 256;
    unsigned* counter  = (unsigned*)(partial2 + (size_t)TAIL_NB * 256);

    hipLaunchKernelGGL(conv1d_train_main, dim3(NB), dim3(256), 0, stream,
                       x, y, kern, bias, partial);
    hipLaunchKernelGGL(conv1d_train_tail, dim3(TAIL_NB), dim3(1024), 0, stream,
                       partial, partial2, counter, kern, bias, out);
}